// Round 1
// baseline (854.704 us; speedup 1.0000x reference)
//
#include <hip/hip_runtime.h>
#include <hip/hip_bf16.h>

#define NEGV (-1e30f)

__device__ __forceinline__ float laddexp(float a, float b) {
    float m = fmaxf(a, b);
    float n = fminf(a, b);
    // exp(n-m) <= 1; if both are NEGV, n-m=0 -> m + log(2), still ~NEGV
    return m + log1pf(__expf(n - m));
}

// ---------------------------------------------------------------------------
// Kernel 1: per-(b,t) log-softmax denominator + gather of the 101 vocab
// entries the CTC recursion actually uses (blank + L targets).
// grid = (T, B), block = 256. V must be 1024 (256 threads x float4).
// Output: gat[b][t][j], j=0 -> blank, j=1+l -> target l.  (G = L+1 floats/row)
// ---------------------------------------------------------------------------
__global__ void lse_gather_kernel(const float* __restrict__ pred,
                                  const int* __restrict__ tgt,
                                  float* __restrict__ gat,
                                  int T, int V, int L) {
    const int t = blockIdx.x;
    const int b = blockIdx.y;
    const int tid = threadIdx.x;
    const float* row = pred + ((size_t)b * T + t) * V;

    float4 v = ((const float4*)row)[tid];
    float m = fmaxf(fmaxf(v.x, v.y), fmaxf(v.z, v.w));
    #pragma unroll
    for (int off = 32; off; off >>= 1) m = fmaxf(m, __shfl_down(m, off, 64));

    __shared__ float sm[4];
    __shared__ float ss[4];
    const int wave = tid >> 6, lane = tid & 63;
    if (lane == 0) sm[wave] = m;
    __syncthreads();
    if (tid == 0) sm[0] = fmaxf(fmaxf(sm[0], sm[1]), fmaxf(sm[2], sm[3]));
    __syncthreads();
    const float mm = sm[0];

    float s = __expf(v.x - mm) + __expf(v.y - mm) + __expf(v.z - mm) + __expf(v.w - mm);
    #pragma unroll
    for (int off = 32; off; off >>= 1) s += __shfl_down(s, off, 64);
    if (lane == 0) ss[wave] = s;
    __syncthreads();
    if (tid == 0) ss[0] = (ss[0] + ss[1]) + (ss[2] + ss[3]);
    __syncthreads();
    const float lse = mm + logf(ss[0]);

    const int G = L + 1;
    float* out = gat + ((size_t)b * T + t) * G;
    for (int j = tid; j < G; j += blockDim.x) {
        int vidx = (j == 0) ? 0 : tgt[b * L + j - 1];   // row just read -> L1 hit
        out[j] = row[vidx] - lse;
    }
}

// ---------------------------------------------------------------------------
// Kernel 2: CTC alpha recursion. One block per batch element, thread s owns
// extended state s (S = 2L+1 states). Ping-pong alpha in LDS, one barrier per
// time step, prefetch of next step's gathered log-prob.
// ---------------------------------------------------------------------------
__global__ void ctc_alpha_kernel(const float* __restrict__ gat,
                                 const int* __restrict__ tgt,
                                 const int* __restrict__ in_len,
                                 const int* __restrict__ tg_len,
                                 float* __restrict__ out,
                                 int T, int L, int B) {
    const int b = blockIdx.x;
    const int s = threadIdx.x;
    const int S = 2 * L + 1;
    const int G = L + 1;

    extern __shared__ float buf[];          // 2 * S floats
    float* cur = buf;
    float* nxt = buf + S;

    const int il = in_len[b];
    const int tl = tg_len[b];

    // per-thread constants: gather column j, skip-transition flag
    int j = 0;
    bool skip = false;
    if (s < S) {
        if (s & 1) {
            j = (s >> 1) + 1;
            int myext = tgt[b * L + (s >> 1)];
            if (s >= 2) {
                int e2 = ((s - 2) & 1) ? tgt[b * L + ((s - 2) >> 1)] : 0;
                skip = (myext != 0) && (myext != e2);
            }
        } else {
            j = 0;          // blank
        }
    }

    const float* gb = gat + (size_t)b * T * G;

    // t = 0 init
    if (s < S) {
        float a0 = NEGV;
        if (s == 0) a0 = gb[0];
        else if (s == 1) a0 = (tl > 0) ? gb[1] : NEGV;
        cur[s] = a0;
    }
    __syncthreads();

    const int e1 = 2 * tl;
    const int e2i = max(2 * tl - 1, 0);
    float final_v = NEGV;
    if (s == 0 && il == 1) final_v = laddexp(cur[e1], cur[e2i]);

    // prefetch t=1 gathered lp
    float lp_next = (s < S && T > 1) ? gb[(size_t)G + j] : NEGV;

    for (int t = 1; t < T; ++t) {
        float lp = lp_next;
        if (s < S && t + 1 < T) lp_next = gb[(size_t)(t + 1) * G + j];  // issued early

        float a  = (s < S) ? cur[s] : NEGV;
        float p1 = (s >= 1 && s < S) ? cur[s - 1] : NEGV;
        float p2 = skip ? cur[s - 2] : NEGV;
        float na = laddexp(laddexp(a, p1), p2) + lp;
        float val = (t < il) ? na : a;
        if (s < S) nxt[s] = val;
        __syncthreads();   // writes to 'cur' next iter are safe: reads done before here

        if (s == 0 && t == il - 1) final_v = laddexp(nxt[e1], nxt[e2i]);

        float* tmp = cur; cur = nxt; nxt = tmp;
    }

    if (s == 0) {
        float loss = (final_v <= NEGV * 0.5f) ? 0.0f : -final_v;
        atomicAdd(out, loss / ((float)tl * (float)B));
    }
}

__global__ void zero_out_kernel(float* out) { out[0] = 0.0f; }

extern "C" void kernel_launch(void* const* d_in, const int* in_sizes, int n_in,
                              void* d_out, int out_size, void* d_ws, size_t ws_size,
                              hipStream_t stream) {
    const float* pred = (const float*)d_in[0];
    const int*   plen = (const int*)d_in[1];
    const int*   gt   = (const int*)d_in[2];
    const int*   glen = (const int*)d_in[3];
    float* out = (float*)d_out;

    const int B = in_sizes[1];
    const int L = in_sizes[2] / B;
    const int V = 1024;                      // problem-fixed (reference setup)
    const int T = in_sizes[0] / B / V;
    const int S = 2 * L + 1;

    float* gat = (float*)d_ws;               // B*T*(L+1) floats = ~12.3 MiB

    zero_out_kernel<<<1, 1, 0, stream>>>(out);

    dim3 g1(T, B);
    lse_gather_kernel<<<g1, 256, 0, stream>>>(pred, gt, gat, T, V, L);

    int blk = ((S + 63) / 64) * 64;          // 256 for L=100
    ctc_alpha_kernel<<<B, blk, 2 * S * sizeof(float), stream>>>(
        gat, gt, plen, glen, out, T, L, B);
}

// Round 4
// 767.180 us; speedup vs baseline: 1.1141x; 1.1141x over previous
//
#include <hip/hip_runtime.h>
#include <hip/hip_bf16.h>

#define NEGV (-1e30f)

__device__ __forceinline__ float laddexp(float a, float b) {
    float m = fmaxf(a, b);
    float n = fminf(a, b);
    // both NEGV -> m + ln2 (still ~NEGV); one NEGV -> exp(-huge)=0 -> m
    return m + __logf(1.0f + __expf(n - m));
}

// ---------------------------------------------------------------------------
// Kernel 1: one WAVE per (b,t) row. 64 lanes x FOUR float4 = 1024 = V.
// Butterfly shuffle reductions (no LDS, no barriers).
// Output gat[b][t][j]: j=0 -> blank, j=1+l -> target l.  G = L+1.
// ---------------------------------------------------------------------------
__global__ void lse_gather_kernel(const float* __restrict__ pred,
                                  const int* __restrict__ tgt,
                                  float* __restrict__ gat,
                                  int T, int V, int L, int nrows) {
    const int wid = blockIdx.x * (blockDim.x >> 6) + (threadIdx.x >> 6);
    if (wid >= nrows) return;
    const int lane = threadIdx.x & 63;
    const int b = wid / T;

    const float* row = pred + (size_t)wid * V;   // wid == b*T + t
    // 16 floats per lane: 64 lanes x 16 = 1024 = V  (R2 bug: only 1 float4!)
    float4 w0 = ((const float4*)row)[lane];
    float4 w1 = ((const float4*)row)[lane + 64];
    float4 w2 = ((const float4*)row)[lane + 128];
    float4 w3 = ((const float4*)row)[lane + 192];

    float m = fmaxf(fmaxf(fmaxf(w0.x, w0.y), fmaxf(w0.z, w0.w)),
                    fmaxf(fmaxf(w1.x, w1.y), fmaxf(w1.z, w1.w)));
    m = fmaxf(m, fmaxf(fmaxf(w2.x, w2.y), fmaxf(w2.z, w2.w)));
    m = fmaxf(m, fmaxf(fmaxf(w3.x, w3.y), fmaxf(w3.z, w3.w)));
    #pragma unroll
    for (int off = 1; off < 64; off <<= 1) m = fmaxf(m, __shfl_xor(m, off, 64));

    float s = __expf(w0.x - m) + __expf(w0.y - m) + __expf(w0.z - m) + __expf(w0.w - m)
            + __expf(w1.x - m) + __expf(w1.y - m) + __expf(w1.z - m) + __expf(w1.w - m)
            + __expf(w2.x - m) + __expf(w2.y - m) + __expf(w2.z - m) + __expf(w2.w - m)
            + __expf(w3.x - m) + __expf(w3.y - m) + __expf(w3.z - m) + __expf(w3.w - m);
    #pragma unroll
    for (int off = 1; off < 64; off <<= 1) s += __shfl_xor(s, off, 64);

    const float lse = m + __logf(s);

    const int G = L + 1;
    float* outr = gat + (size_t)wid * G;
    for (int j = lane; j < G; j += 64) {
        int vidx = (j == 0) ? 0 : tgt[b * L + j - 1];   // row is L1-hot
        outr[j] = row[vidx] - lse;
    }
}

// ---------------------------------------------------------------------------
// Kernel 2: CTC alpha recursion, ONE WAVE per batch element.
// Lane k owns extended states 4k..4k+3 (S = 2L+1 = 201 -> 51 active lanes).
// Neighbor states via __shfl_up; no LDS, no __syncthreads in the T-loop.
// Gathered log-probs prefetched through a depth-4 register ring so global
// loads stay in flight across iterations (no vmcnt(0) drain on the path).
//
// Transition map (lane k states: s0=4k bl, s1=4k+1 lab2k, s2=4k+2 bl,
// s3=4k+3 lab2k+1; pm1 = lane(k-1).a3 = state 4k-1):
//   n0: {a0, pm1}            n1: {a1, a0, skip: pm1}
//   n2: {a2, a1}             n3: {a3, a2, skip: a1}
// ---------------------------------------------------------------------------
__global__ void ctc_alpha_wave(const float* __restrict__ gat,
                               const int* __restrict__ tgt,
                               const int* __restrict__ in_len,
                               const int* __restrict__ tg_len,
                               float* __restrict__ out,
                               int T, int L, int B) {
    const int b = blockIdx.x;
    const int k = threadIdx.x;          // lane in the single wave (block=64)
    const int S = 2 * L + 1;
    const int G = L + 1;

    const int il = in_len[b];
    const int tl = tg_len[b];
    const float* gb = gat + (size_t)b * T * G;

    const int s0 = 4 * k;
    const bool v0 = (s0     < S);
    const bool v1 = (s0 + 1 < S);
    const bool v2 = (s0 + 2 < S);
    const bool v3 = (s0 + 3 < S);

    const int c1 = v1 ? (2 * k + 1) : 0;     // gat column for state s1
    const int c2 = v3 ? (2 * k + 2) : 0;     // gat column for state s3

    bool sk1 = false, sk3 = false;
    if (v1 && k > 0) {                        // s1 >= 2  <=>  k >= 1
        int l = 2 * k;
        int tc = tgt[b * L + l], tp = tgt[b * L + l - 1];
        sk1 = (tc != 0) && (tc != tp);
    }
    if (v3) {                                 // s3 >= 3 always
        int l = 2 * k + 1;
        int tc = tgt[b * L + l], tp = tgt[b * L + l - 1];
        sk3 = (tc != 0) && (tc != tp);
    }

    // t = 0 init
    float a0 = NEGV, a1 = NEGV, a2 = NEGV, a3 = NEGV;
    if (k == 0) {
        a0 = gb[0];
        a1 = (tl > 0) ? gb[1] : NEGV;
    }

    const int e1 = 2 * tl;
    const int e2 = (2 * tl - 1 > 0) ? (2 * tl - 1) : 0;
    const int i1 = e1 & 3, l1 = e1 >> 2;
    const int i2 = e2 & 3, l2 = e2 >> 2;

    float final_v = NEGV;
    {
        float m1 = (i1 == 0) ? a0 : (i1 == 1) ? a1 : (i1 == 2) ? a2 : a3;
        float m2 = (i2 == 0) ? a0 : (i2 == 1) ? a1 : (i2 == 2) ? a2 : a3;
        float ev1 = __shfl(m1, l1, 64);
        float ev2 = __shfl(m2, l2, 64);
        if (il == 1) final_v = laddexp(ev1, ev2);
    }

    // depth-4 prefetch ring
    float Pb[4], P1[4], P2[4];
    #pragma unroll
    for (int d = 0; d < 4; ++d) {
        int tt = 1 + d;
        if (tt < T) {
            const float* r = gb + (size_t)tt * G;
            Pb[d] = r[0]; P1[d] = r[c1]; P2[d] = r[c2];
        } else { Pb[d] = NEGV; P1[d] = NEGV; P2[d] = NEGV; }
    }

    int t = 1;

#define CTC_STEP(d)                                                          \
    {                                                                        \
        float lpb = Pb[d], lpx = P1[d], lpy = P2[d];                         \
        int tp = t + 4;                                                      \
        if (tp < T) {                                                        \
            const float* r = gb + (size_t)tp * G;                            \
            Pb[d] = r[0]; P1[d] = r[c1]; P2[d] = r[c2];                      \
        }                                                                    \
        float pm1 = __shfl_up(a3, 1, 64);     /* state 4k-1 from lane k-1 */ \
        if (k == 0) pm1 = NEGV;                                              \
        float n0 = laddexp(a0, pm1) + lpb;                                   \
        float n1 = laddexp(laddexp(a1, a0), sk1 ? pm1 : NEGV) + lpx;         \
        float n2 = laddexp(a2, a1) + lpb;                                    \
        float n3 = laddexp(laddexp(a3, a2), sk3 ? a1 : NEGV) + lpy;          \
        bool upd = (t < il);                                                 \
        a0 = (upd && v0) ? n0 : a0;                                          \
        a1 = (upd && v1) ? n1 : a1;                                          \
        a2 = (upd && v2) ? n2 : a2;                                          \
        a3 = (upd && v3) ? n3 : a3;                                          \
        if (t == il - 1) {                                                   \
            float m1 = (i1 == 0) ? a0 : (i1 == 1) ? a1 : (i1 == 2) ? a2 : a3;\
            float m2 = (i2 == 0) ? a0 : (i2 == 1) ? a1 : (i2 == 2) ? a2 : a3;\
            float ev1 = __shfl(m1, l1, 64);                                  \
            float ev2 = __shfl(m2, l2, 64);                                  \
            final_v = laddexp(ev1, ev2);                                     \
        }                                                                    \
        ++t;                                                                 \
    }

    while (t + 4 <= T) { CTC_STEP(0) CTC_STEP(1) CTC_STEP(2) CTC_STEP(3) }
    if (t < T) { CTC_STEP(0)
        if (t < T) { CTC_STEP(1)
            if (t < T) { CTC_STEP(2) } } }
#undef CTC_STEP

    if (k == 0) {
        float loss = (final_v <= NEGV * 0.5f) ? 0.0f : -final_v;
        atomicAdd(out, loss / ((float)tl * (float)B));
    }
}

__global__ void zero_out_kernel(float* out) { out[0] = 0.0f; }

extern "C" void kernel_launch(void* const* d_in, const int* in_sizes, int n_in,
                              void* d_out, int out_size, void* d_ws, size_t ws_size,
                              hipStream_t stream) {
    const float* pred = (const float*)d_in[0];
    const int*   plen = (const int*)d_in[1];
    const int*   gt   = (const int*)d_in[2];
    const int*   glen = (const int*)d_in[3];
    float* out = (float*)d_out;

    const int B = in_sizes[1];
    const int L = in_sizes[2] / B;
    const int V = 1024;                      // problem-fixed (reference setup)
    const int T = in_sizes[0] / B / V;

    float* gat = (float*)d_ws;               // B*T*(L+1) floats = ~12.3 MiB

    zero_out_kernel<<<1, 1, 0, stream>>>(out);

    const int nrows = B * T;                 // one wave per row
    const int wavesPerBlk = 4;               // block = 256
    const int nblk = (nrows + wavesPerBlk - 1) / wavesPerBlk;
    lse_gather_kernel<<<nblk, 64 * wavesPerBlk, 0, stream>>>(
        pred, gt, gat, T, V, L, nrows);

    ctc_alpha_wave<<<B, 64, 0, stream>>>(gat, gt, plen, glen, out, T, L, B);
}

// Round 6
// 495.233 us; speedup vs baseline: 1.7259x; 1.5491x over previous
//
#include <hip/hip_runtime.h>
#include <hip/hip_bf16.h>

#define NEGV (-1e30f)

// log2-domain logaddexp: a,b are log2-probs.
// exp2f/log2f are the NATIVE AMD transcendentals (v_exp_f32/v_log_f32 are
// base-2 in HW); __exp2f does not exist in HIP device code.
__device__ __forceinline__ float laddexp2_2(float a, float b) {
    float m = fmaxf(a, b);
    float n = fminf(a, b);
    return m + log2f(1.0f + exp2f(n - m));   // both NEGV -> m+1, still ~NEGV
}
__device__ __forceinline__ float laddexp2_3(float a, float b, float c) {
    float m = fmaxf(fmaxf(a, b), c);             // v_max3_f32
    float s = exp2f(a - m) + exp2f(b - m) + exp2f(c - m);
    return m + log2f(s);
}

// ---------------------------------------------------------------------------
// Kernel 1: one WAVE per (b,t) row; 64 lanes x 16 floats = 1024 = V.
// Emits gat2[row][lane] = float4{ lp2(lab 2k), lp2(lab 2k+1), lp2(blank), 0 }
// (log2 domain), so the alpha kernel does ONE dwordx4 per lane per step.
// Also zeroes out[0] (block 0) so no separate zero kernel is needed.
// ---------------------------------------------------------------------------
__global__ void lse_gather_kernel(const float* __restrict__ pred,
                                  const int* __restrict__ tgt,
                                  float4* __restrict__ gat,
                                  float* __restrict__ out,
                                  int T, int V, int L, int nrows) {
    if (blockIdx.x == 0 && threadIdx.x == 0) out[0] = 0.0f;

    const int wid = blockIdx.x * (blockDim.x >> 6) + (threadIdx.x >> 6);
    if (wid >= nrows) return;
    const int lane = threadIdx.x & 63;
    const int b = wid / T;

    const float* row = pred + (size_t)wid * V;   // wid == b*T + t
    float4 w0 = ((const float4*)row)[lane];
    float4 w1 = ((const float4*)row)[lane + 64];
    float4 w2 = ((const float4*)row)[lane + 128];
    float4 w3 = ((const float4*)row)[lane + 192];

    float m = fmaxf(fmaxf(fmaxf(w0.x, w0.y), fmaxf(w0.z, w0.w)),
                    fmaxf(fmaxf(w1.x, w1.y), fmaxf(w1.z, w1.w)));
    m = fmaxf(m, fmaxf(fmaxf(w2.x, w2.y), fmaxf(w2.z, w2.w)));
    m = fmaxf(m, fmaxf(fmaxf(w3.x, w3.y), fmaxf(w3.z, w3.w)));
    #pragma unroll
    for (int off = 1; off < 64; off <<= 1) m = fmaxf(m, __shfl_xor(m, off, 64));

    float s = __expf(w0.x - m) + __expf(w0.y - m) + __expf(w0.z - m) + __expf(w0.w - m)
            + __expf(w1.x - m) + __expf(w1.y - m) + __expf(w1.z - m) + __expf(w1.w - m)
            + __expf(w2.x - m) + __expf(w2.y - m) + __expf(w2.z - m) + __expf(w2.w - m)
            + __expf(w3.x - m) + __expf(w3.y - m) + __expf(w3.z - m) + __expf(w3.w - m);
    #pragma unroll
    for (int off = 1; off < 64; off <<= 1) s += __shfl_xor(s, off, 64);

    const float lse = m + __logf(s);
    const float K2 = 1.4426950408889634f;   // log2(e)

    float bl = (row[0] - lse) * K2;
    float y0 = 0.0f, y1 = 0.0f;
    const int l0 = 2 * lane, l1i = 2 * lane + 1;
    if (l0  < L) y0 = (row[tgt[b * L + l0 ]] - lse) * K2;   // row is L1-hot
    if (l1i < L) y1 = (row[tgt[b * L + l1i]] - lse) * K2;

    float4 o; o.x = y0; o.y = y1; o.z = bl; o.w = 0.0f;
    gat[(size_t)wid * 64 + lane] = o;
}

// ---------------------------------------------------------------------------
// Kernel 2: CTC alpha recursion, ONE WAVE per batch element, log2 domain.
// Lane k owns states 4k..4k+3. Per step: 1 dwordx4 (depth-8 ring),
// 1 ds_permute, 6 logaddexps. No cndmask updates, no in-loop final capture:
// loop runs t = 1 .. min(il,T)-1, final evaluated once afterwards
// (alpha is frozen for t >= il; reference computes all S states likewise).
// ---------------------------------------------------------------------------
__global__ void ctc_alpha_wave(const float4* __restrict__ gat,
                               const int* __restrict__ tgt,
                               const int* __restrict__ in_len,
                               const int* __restrict__ tg_len,
                               float* __restrict__ out,
                               int T, int L, int B) {
    const int b = blockIdx.x;
    const int k = threadIdx.x;              // single wave, block = 64
    const int S = 2 * L + 1;

    const int il = in_len[b];
    const int tl = tg_len[b];
    const float4* gb = gat + (size_t)b * T * 64;

    const bool v1 = (4 * k + 1 < S);        // label 2k exists
    const bool v3 = (4 * k + 3 < S);        // label 2k+1 exists
    bool sk1 = false, sk3 = false;
    if (v1 && k > 0) {
        int tc = tgt[b * L + 2 * k], tp = tgt[b * L + 2 * k - 1];
        sk1 = (tc != 0) && (tc != tp);
    }
    if (v3) {
        int tc = tgt[b * L + 2 * k + 1], tp = tgt[b * L + 2 * k];
        sk3 = (tc != 0) && (tc != tp);
    }

    // t = 0 init (log2 domain)
    float a0 = NEGV, a1 = NEGV, a2 = NEGV, a3 = NEGV;
    {
        float4 f0 = gb[k];
        if (k == 0) { a0 = f0.z; a1 = (tl > 0) ? f0.x : NEGV; }
    }

    const int tmax = (il < T) ? il : T;

    // depth-8 prefetch ring (rows clamped to T-1; redundant loads harmless)
    float4 P[8];
    #pragma unroll
    for (int d = 0; d < 8; ++d) {
        int r = 1 + d; if (r > T - 1) r = T - 1;
        P[d] = gb[(size_t)r * 64 + k];
    }

    int t = 1;

#define STEP(d)                                                              \
    {                                                                        \
        float4 p = P[d];                                                     \
        int r = t + 8; if (r > T - 1) r = T - 1;                             \
        P[d] = gb[(size_t)r * 64 + k];                                       \
        float pm1 = __shfl_up(a3, 1, 64);     /* state 4k-1 from lane k-1 */ \
        if (k == 0) pm1 = NEGV;                                              \
        float n0 = laddexp2_2(a0, pm1) + p.z;                                \
        float n1 = laddexp2_3(a1, a0, sk1 ? pm1 : NEGV) + p.x;               \
        float n2 = laddexp2_2(a2, a1) + p.z;                                 \
        float n3 = laddexp2_3(a3, a2, sk3 ? a1 : NEGV) + p.y;                \
        a0 = n0; a1 = n1; a2 = n2; a3 = n3;                                  \
        ++t;                                                                 \
    }

    while (t + 8 <= tmax) {
        STEP(0) STEP(1) STEP(2) STEP(3) STEP(4) STEP(5) STEP(6) STEP(7)
    }
    if (t < tmax) { STEP(0)
    if (t < tmax) { STEP(1)
    if (t < tmax) { STEP(2)
    if (t < tmax) { STEP(3)
    if (t < tmax) { STEP(4)
    if (t < tmax) { STEP(5)
    if (t < tmax) { STEP(6) } } } } } } }
#undef STEP

    // final = logaddexp(alpha[2*tl], alpha[2*tl-1]) at t = il-1 (current a's)
    const int e1 = 2 * tl;
    const int e2 = (2 * tl - 1 > 0) ? (2 * tl - 1) : 0;
    const int i1 = e1 & 3, l1 = e1 >> 2;
    const int i2 = e2 & 3, l2 = e2 >> 2;
    float m1 = (i1 == 0) ? a0 : (i1 == 1) ? a1 : (i1 == 2) ? a2 : a3;
    float m2 = (i2 == 0) ? a0 : (i2 == 1) ? a1 : (i2 == 2) ? a2 : a3;
    float ev1 = __shfl(m1, l1, 64);
    float ev2 = __shfl(m2, l2, 64);
    float fin = laddexp2_2(ev1, ev2);
    if (il < 1 || il > T) fin = NEGV;       // reference: final never set -> 0

    if (k == 0) {
        float loss = (fin <= NEGV * 0.5f) ? 0.0f
                                          : -fin * 0.6931471805599453f; // ln2
        atomicAdd(out, loss / ((float)tl * (float)B));
    }
}

extern "C" void kernel_launch(void* const* d_in, const int* in_sizes, int n_in,
                              void* d_out, int out_size, void* d_ws, size_t ws_size,
                              hipStream_t stream) {
    const float* pred = (const float*)d_in[0];
    const int*   plen = (const int*)d_in[1];
    const int*   gt   = (const int*)d_in[2];
    const int*   glen = (const int*)d_in[3];
    float* out = (float*)d_out;

    const int B = in_sizes[1];
    const int L = in_sizes[2] / B;
    const int V = 1024;                      // problem-fixed (reference setup)
    const int T = in_sizes[0] / B / V;

    float4* gat = (float4*)d_ws;             // B*T*64 float4 = ~32.8 MiB

    const int nrows = B * T;                 // one wave per row
    const int wavesPerBlk = 4;               // block = 256
    const int nblk = (nrows + wavesPerBlk - 1) / wavesPerBlk;
    lse_gather_kernel<<<nblk, 64 * wavesPerBlk, 0, stream>>>(
        pred, gt, gat, out, T, V, L, nrows);

    ctc_alpha_wave<<<B, 64, 0, stream>>>(gat, gt, plen, glen, out, T, L, B);
}

// Round 7
// 305.962 us; speedup vs baseline: 2.7935x; 1.6186x over previous
//
#include <hip/hip_runtime.h>
#include <hip/hip_bf16.h>

#define NEGV (-1e30f)

#if __has_builtin(__builtin_amdgcn_exp2f)
#define EXP2(x) __builtin_amdgcn_exp2f(x)
#else
#define EXP2(x) exp2f(x)
#endif
#if __has_builtin(__builtin_amdgcn_logf)
#define LOG2(x) __builtin_amdgcn_logf(x)
#else
#define LOG2(x) log2f(x)
#endif

__device__ __forceinline__ float laddexp2_2(float a, float b) {
    float m = fmaxf(a, b);
    float n = fminf(a, b);
    return m + LOG2(1.0f + EXP2(n - m));
}

// ---------------------------------------------------------------------------
// Kernel 1: one WAVE per (b,t) row; 64 lanes x 16 floats = 1024 = V.
// Emits gat[row][lane] = float4{ lp2(lab 2k), lp2(lab 2k+1), lp2(blank), 0 }
// (log2 domain). Also zeroes out[0] (block 0).
// ---------------------------------------------------------------------------
__global__ void lse_gather_kernel(const float* __restrict__ pred,
                                  const int* __restrict__ tgt,
                                  float4* __restrict__ gat,
                                  float* __restrict__ out,
                                  int T, int V, int L, int nrows) {
    if (blockIdx.x == 0 && threadIdx.x == 0) out[0] = 0.0f;

    const int wid = blockIdx.x * (blockDim.x >> 6) + (threadIdx.x >> 6);
    if (wid >= nrows) return;
    const int lane = threadIdx.x & 63;
    const int b = wid / T;

    const float* row = pred + (size_t)wid * V;   // wid == b*T + t
    float4 w0 = ((const float4*)row)[lane];
    float4 w1 = ((const float4*)row)[lane + 64];
    float4 w2 = ((const float4*)row)[lane + 128];
    float4 w3 = ((const float4*)row)[lane + 192];

    float m = fmaxf(fmaxf(fmaxf(w0.x, w0.y), fmaxf(w0.z, w0.w)),
                    fmaxf(fmaxf(w1.x, w1.y), fmaxf(w1.z, w1.w)));
    m = fmaxf(m, fmaxf(fmaxf(w2.x, w2.y), fmaxf(w2.z, w2.w)));
    m = fmaxf(m, fmaxf(fmaxf(w3.x, w3.y), fmaxf(w3.z, w3.w)));
    #pragma unroll
    for (int off = 1; off < 64; off <<= 1) m = fmaxf(m, __shfl_xor(m, off, 64));

    float s = __expf(w0.x - m) + __expf(w0.y - m) + __expf(w0.z - m) + __expf(w0.w - m)
            + __expf(w1.x - m) + __expf(w1.y - m) + __expf(w1.z - m) + __expf(w1.w - m)
            + __expf(w2.x - m) + __expf(w2.y - m) + __expf(w2.z - m) + __expf(w2.w - m)
            + __expf(w3.x - m) + __expf(w3.y - m) + __expf(w3.z - m) + __expf(w3.w - m);
    #pragma unroll
    for (int off = 1; off < 64; off <<= 1) s += __shfl_xor(s, off, 64);

    const float lse = m + __logf(s);
    const float K2 = 1.4426950408889634f;   // log2(e)

    float bl = (row[0] - lse) * K2;
    float y0 = 0.0f, y1 = 0.0f;
    const int l0 = 2 * lane, l1i = 2 * lane + 1;
    if (l0  < L) y0 = (row[tgt[b * L + l0 ]] - lse) * K2;   // row is L1-hot
    if (l1i < L) y1 = (row[tgt[b * L + l1i]] - lse) * K2;

    float4 o; o.x = y0; o.y = y1; o.z = bl; o.w = 0.0f;
    gat[(size_t)wid * 64 + lane] = o;
}

// ---------------------------------------------------------------------------
// Kernel 2: CTC alpha, ONE WAVE per batch element, log2 domain.
// Lane k owns states 4k..4k+3.  Per step:
//   - n2/n3 first (no neighbor dep), immediately ISSUE shfl_up(n3) for the
//     NEXT step, then consume the PREVIOUS shfl result for n0/n1 -> the
//     ~120cyc DS latency overlaps ~80cyc of independent ALU.
//   - two shared-max transcendental groups (10 trans/step vs 12), raw
//     v_exp_f32/v_log_f32; fmaxf(.,NEGV) re-clamp keeps sentinel finite.
//   - 16-deep NAMED register prefetch ring (covers ~900cyc HBM miss).
// Transition map (pm = lane(k-1).a3 = state 4k-1):
//   n0:{a0,pm}  n1:{a1,a0,skip:pm}  n2:{a2,a1}  n3:{a3,a2,skip:a1}
// ---------------------------------------------------------------------------
__global__ void ctc_alpha_wave(const float4* __restrict__ gat,
                               const int* __restrict__ tgt,
                               const int* __restrict__ in_len,
                               const int* __restrict__ tg_len,
                               float* __restrict__ out,
                               int T, int L, int B) {
    const int b = blockIdx.x;
    const int k = threadIdx.x;              // single wave, block = 64
    const int S = 2 * L + 1;

    const int il = in_len[b];
    const int tl = tg_len[b];
    const float4* gb = gat + (size_t)b * T * 64;

    const bool v1 = (4 * k + 1 < S);
    const bool v3 = (4 * k + 3 < S);
    bool sk1 = false, sk3 = false;
    if (v1 && k > 0) {
        int tc = tgt[b * L + 2 * k], tp = tgt[b * L + 2 * k - 1];
        sk1 = (tc != 0) && (tc != tp);
    }
    if (v3) {
        int tc = tgt[b * L + 2 * k + 1], tp = tgt[b * L + 2 * k];
        sk3 = (tc != 0) && (tc != tp);
    }

    // t = 0 init (log2 domain)
    float a0 = NEGV, a1 = NEGV, a2 = NEGV, a3 = NEGV;
    {
        float4 f0 = gb[k];
        if (k == 0) { a0 = f0.z; a1 = (tl > 0) ? f0.x : NEGV; }
    }

    const int tmax = (il < T) ? il : T;
    const int rmax = T - 1;

    // 16-deep named prefetch ring
    float4 P0,P1,P2,P3,P4,P5,P6,P7,P8,P9,P10,P11,P12,P13,P14,P15;
    {
        int r;
        r = (1  > rmax) ? rmax : 1;  P0  = gb[(size_t)r * 64 + k];
        r = (2  > rmax) ? rmax : 2;  P1  = gb[(size_t)r * 64 + k];
        r = (3  > rmax) ? rmax : 3;  P2  = gb[(size_t)r * 64 + k];
        r = (4  > rmax) ? rmax : 4;  P3  = gb[(size_t)r * 64 + k];
        r = (5  > rmax) ? rmax : 5;  P4  = gb[(size_t)r * 64 + k];
        r = (6  > rmax) ? rmax : 6;  P5  = gb[(size_t)r * 64 + k];
        r = (7  > rmax) ? rmax : 7;  P6  = gb[(size_t)r * 64 + k];
        r = (8  > rmax) ? rmax : 8;  P7  = gb[(size_t)r * 64 + k];
        r = (9  > rmax) ? rmax : 9;  P8  = gb[(size_t)r * 64 + k];
        r = (10 > rmax) ? rmax : 10; P9  = gb[(size_t)r * 64 + k];
        r = (11 > rmax) ? rmax : 11; P10 = gb[(size_t)r * 64 + k];
        r = (12 > rmax) ? rmax : 12; P11 = gb[(size_t)r * 64 + k];
        r = (13 > rmax) ? rmax : 13; P12 = gb[(size_t)r * 64 + k];
        r = (14 > rmax) ? rmax : 14; P13 = gb[(size_t)r * 64 + k];
        r = (15 > rmax) ? rmax : 15; P14 = gb[(size_t)r * 64 + k];
        r = (16 > rmax) ? rmax : 16; P15 = gb[(size_t)r * 64 + k];
    }

    // pm for step t=1: shfl_up of a3 at t=0
    float pm1 = __shfl_up(a3, 1, 64);

    int t = 1;

#define STEP(PP)                                                             \
    {                                                                        \
        float4 p = PP;                                                       \
        int r = t + 16; r = (r > rmax) ? rmax : r;                           \
        PP = gb[(size_t)r * 64 + k];                                         \
        /* group 2/3: no neighbor dependence */                              \
        float m23 = fmaxf(fmaxf(a1, a2), a3);                                \
        float E1b = EXP2(a1 - m23), E2b = EXP2(a2 - m23),                    \
              E3b = EXP2(a3 - m23);                                          \
        float n2 = m23 + LOG2(E2b + E1b) + p.z;                              \
        float n3 = m23 + LOG2(E3b + E2b + (sk3 ? E1b : 0.0f)) + p.y;        \
        n2 = fmaxf(n2, NEGV); n3 = fmaxf(n3, NEGV);                          \
        float pm_next = __shfl_up(n3, 1, 64);   /* issue for NEXT step */    \
        /* group 0/1: consume PREVIOUS shfl */                               \
        float pm = (k == 0) ? NEGV : pm1;                                    \
        float m01 = fmaxf(fmaxf(a0, a1), pm);                                \
        float E0 = EXP2(a0 - m01), E1a = EXP2(a1 - m01),                     \
              Ep = EXP2(pm - m01);                                           \
        float n0 = m01 + LOG2(E0 + Ep) + p.z;                                \
        float n1 = m01 + LOG2(E1a + E0 + (sk1 ? Ep : 0.0f)) + p.x;          \
        n0 = fmaxf(n0, NEGV); n1 = fmaxf(n1, NEGV);                          \
        a0 = n0; a1 = n1; a2 = n2; a3 = n3; pm1 = pm_next;                   \
        ++t;                                                                 \
    }

    while (t + 16 <= tmax) {
        STEP(P0)  STEP(P1)  STEP(P2)  STEP(P3)
        STEP(P4)  STEP(P5)  STEP(P6)  STEP(P7)
        STEP(P8)  STEP(P9)  STEP(P10) STEP(P11)
        STEP(P12) STEP(P13) STEP(P14) STEP(P15)
    }
    if (t < tmax) { STEP(P0)
    if (t < tmax) { STEP(P1)
    if (t < tmax) { STEP(P2)
    if (t < tmax) { STEP(P3)
    if (t < tmax) { STEP(P4)
    if (t < tmax) { STEP(P5)
    if (t < tmax) { STEP(P6)
    if (t < tmax) { STEP(P7)
    if (t < tmax) { STEP(P8)
    if (t < tmax) { STEP(P9)
    if (t < tmax) { STEP(P10)
    if (t < tmax) { STEP(P11)
    if (t < tmax) { STEP(P12)
    if (t < tmax) { STEP(P13)
    if (t < tmax) { STEP(P14) } } } } } } } } } } } } } } }
#undef STEP

    // final = logaddexp(alpha[2*tl], alpha[2*tl-1]) at t = il-1
    const int e1 = 2 * tl;
    const int e2 = (2 * tl - 1 > 0) ? (2 * tl - 1) : 0;
    const int i1 = e1 & 3, l1 = e1 >> 2;
    const int i2 = e2 & 3, l2 = e2 >> 2;
    float m1 = (i1 == 0) ? a0 : (i1 == 1) ? a1 : (i1 == 2) ? a2 : a3;
    float m2 = (i2 == 0) ? a0 : (i2 == 1) ? a1 : (i2 == 2) ? a2 : a3;
    float ev1 = __shfl(m1, l1, 64);
    float ev2 = __shfl(m2, l2, 64);
    float fin = laddexp2_2(ev1, ev2);
    if (il < 1 || il > T) fin = NEGV;       // reference: final never set -> 0

    if (k == 0) {
        float loss = (fin <= NEGV * 0.5f) ? 0.0f
                                          : -fin * 0.6931471805599453f; // ln2
        atomicAdd(out, loss / ((float)tl * (float)B));
    }
}

extern "C" void kernel_launch(void* const* d_in, const int* in_sizes, int n_in,
                              void* d_out, int out_size, void* d_ws, size_t ws_size,
                              hipStream_t stream) {
    const float* pred = (const float*)d_in[0];
    const int*   plen = (const int*)d_in[1];
    const int*   gt   = (const int*)d_in[2];
    const int*   glen = (const int*)d_in[3];
    float* out = (float*)d_out;

    const int B = in_sizes[1];
    const int L = in_sizes[2] / B;
    const int V = 1024;                      // problem-fixed (reference setup)
    const int T = in_sizes[0] / B / V;

    float4* gat = (float4*)d_ws;             // B*T*64 float4 = ~32.8 MiB

    const int nrows = B * T;                 // one wave per row
    const int wavesPerBlk = 4;               // block = 256
    const int nblk = (nrows + wavesPerBlk - 1) / wavesPerBlk;
    lse_gather_kernel<<<nblk, 64 * wavesPerBlk, 0, stream>>>(
        pred, gt, gat, out, T, V, L, nrows);

    ctc_alpha_wave<<<B, 64, 0, stream>>>(gat, gt, plen, glen, out, T, L, B);
}

// Round 8
// 271.592 us; speedup vs baseline: 3.1470x; 1.1266x over previous
//
#include <hip/hip_runtime.h>
#include <hip/hip_bf16.h>

// DPP helper: float lane-crossing via v_mov_b32_dpp (VALU, ~4cyc; no DS).
// bound_ctrl=true -> lanes with invalid source read 0.0f.
#define DPPF(x, ctrl) \
    __int_as_float(__builtin_amdgcn_mov_dpp(__float_as_int(x), (ctrl), 0xf, 0xf, true))

// ---------------------------------------------------------------------------
// Kernel 1: one WAVE per (b,t) row; 64 lanes x 16 floats = 1024 = V.
// Emits gat[row][lane] = float4{ P(lab 2k), P(lab 2k+1), P(blank), 0 } —
// PROBABILITIES (softmax), not log-probs: the alpha recursion runs in the
// linear domain with periodic power-of-2 renorm. Also zeroes out[0].
// ---------------------------------------------------------------------------
__global__ void lse_gather_kernel(const float* __restrict__ pred,
                                  const int* __restrict__ tgt,
                                  float4* __restrict__ gat,
                                  float* __restrict__ out,
                                  int T, int V, int L, int nrows) {
    if (blockIdx.x == 0 && threadIdx.x == 0) out[0] = 0.0f;

    const int wid = blockIdx.x * (blockDim.x >> 6) + (threadIdx.x >> 6);
    if (wid >= nrows) return;
    const int lane = threadIdx.x & 63;
    const int b = wid / T;

    const float* row = pred + (size_t)wid * V;   // wid == b*T + t
    float4 w0 = ((const float4*)row)[lane];
    float4 w1 = ((const float4*)row)[lane + 64];
    float4 w2 = ((const float4*)row)[lane + 128];
    float4 w3 = ((const float4*)row)[lane + 192];

    float m = fmaxf(fmaxf(fmaxf(w0.x, w0.y), fmaxf(w0.z, w0.w)),
                    fmaxf(fmaxf(w1.x, w1.y), fmaxf(w1.z, w1.w)));
    m = fmaxf(m, fmaxf(fmaxf(w2.x, w2.y), fmaxf(w2.z, w2.w)));
    m = fmaxf(m, fmaxf(fmaxf(w3.x, w3.y), fmaxf(w3.z, w3.w)));
    #pragma unroll
    for (int off = 1; off < 64; off <<= 1) m = fmaxf(m, __shfl_xor(m, off, 64));

    float s = __expf(w0.x - m) + __expf(w0.y - m) + __expf(w0.z - m) + __expf(w0.w - m)
            + __expf(w1.x - m) + __expf(w1.y - m) + __expf(w1.z - m) + __expf(w1.w - m)
            + __expf(w2.x - m) + __expf(w2.y - m) + __expf(w2.z - m) + __expf(w2.w - m)
            + __expf(w3.x - m) + __expf(w3.y - m) + __expf(w3.z - m) + __expf(w3.w - m);
    #pragma unroll
    for (int off = 1; off < 64; off <<= 1) s += __shfl_xor(s, off, 64);

    const float lse = m + __logf(s);

    float pz = __expf(row[0] - lse);        // blank probability
    float px = 0.0f, py = 0.0f;             // 0 = additive identity: masks
    const int l0 = 2 * lane, l1i = 2 * lane + 1;
    if (l0  < L) px = __expf(row[tgt[b * L + l0 ]] - lse);  // row is L1-hot
    if (l1i < L) py = __expf(row[tgt[b * L + l1i]] - lse);

    float4 o; o.x = px; o.y = py; o.z = pz; o.w = 0.0f;
    gat[(size_t)wid * 64 + lane] = o;
}

// ---------------------------------------------------------------------------
// Kernel 2: CTC alpha, ONE WAVE per batch element, LINEAR (prob) domain.
// Lane k owns states 4k..4k+3 as probabilities q0..q3 relative to a running
// power-of-2 scale 2^acc. Per step: 1 DPP wave_shr (neighbor q3), 5 add,
// 2 cndmask, 4 mul — NO transcendentals, NO DS ops. Every 4 steps: exact
// power-of-2 renorm (wave max via 6 DPP + readlane -> exponent-only scale,
// integer acc). Invalid states have zero multipliers -> stay exactly 0.
// Transitions: n0:{q0,qm}  n1:{q1,q0,sk:qm}  n2:{q2,q1}  n3:{q3,q2,sk:q1}
// ---------------------------------------------------------------------------
__global__ void ctc_alpha_wave(const float4* __restrict__ gat,
                               const int* __restrict__ tgt,
                               const int* __restrict__ in_len,
                               const int* __restrict__ tg_len,
                               float* __restrict__ out,
                               int T, int L, int B) {
    const int b = blockIdx.x;
    const int k = threadIdx.x;              // single wave, block = 64
    const int S = 2 * L + 1;

    const int il = in_len[b];
    const int tl = tg_len[b];
    const float4* gb = gat + (size_t)b * T * 64;

    const bool v1 = (4 * k + 1 < S);
    const bool v3 = (4 * k + 3 < S);
    bool sk1 = false, sk3 = false;
    if (v1 && k > 0) {
        int tc = tgt[b * L + 2 * k], tp = tgt[b * L + 2 * k - 1];
        sk1 = (tc != 0) && (tc != tp);
    }
    if (v3) {
        int tc = tgt[b * L + 2 * k + 1], tp = tgt[b * L + 2 * k];
        sk3 = (tc != 0) && (tc != tp);
    }

    // t = 0 init (probabilities)
    float q0 = 0.0f, q1 = 0.0f, q2 = 0.0f, q3 = 0.0f;
    {
        float4 f0 = gb[k];
        if (k == 0) { q0 = f0.z; q1 = (tl > 0) ? f0.x : 0.0f; }
    }
    int acc = 0;                            // running log2 scale (integer)

    const int tmax = (il < T) ? il : T;
    const int rmax = T - 1;

    // 24-deep register prefetch ring (Little's law: 24 / ~450cyc L3 latency
    // sustains one row per ~19cyc > consumption rate)
    float4 P[24];
    #pragma unroll
    for (int d = 0; d < 24; ++d) {
        int r = 1 + d; r = (r > rmax) ? rmax : r;
        P[d] = gb[(size_t)r * 64 + k];
    }

    int t = 1;

#define STEP(p)                                                              \
    {                                                                        \
        float qm = DPPF(q3, 0x138);          /* wave_shr:1 -> lane k-1 q3 */ \
        qm = (k == 0) ? 0.0f : qm;                                           \
        float n0 = (q0 + qm) * (p).z;                                        \
        float n1 = (q1 + q0 + (sk1 ? qm : 0.0f)) * (p).x;                    \
        float n2 = (q2 + q1) * (p).z;                                        \
        float n3 = (q3 + q2 + (sk3 ? q1 : 0.0f)) * (p).y;                    \
        q0 = n0; q1 = n1; q2 = n2; q3 = n3;                                  \
        ++t;                                                                 \
    }

// exact power-of-2 renorm: brings wave max's exponent to 0; no rounding.
#define RENORM                                                               \
    {                                                                        \
        float mx = fmaxf(fmaxf(q0, q1), fmaxf(q2, q3));                      \
        mx = fmaxf(mx, DPPF(mx, 0x111));     /* row_shr:1  */                \
        mx = fmaxf(mx, DPPF(mx, 0x112));     /* row_shr:2  */                \
        mx = fmaxf(mx, DPPF(mx, 0x114));     /* row_shr:4  */                \
        mx = fmaxf(mx, DPPF(mx, 0x118));     /* row_shr:8  */                \
        mx = fmaxf(mx, DPPF(mx, 0x142));     /* row_bcast:15 */              \
        mx = fmaxf(mx, DPPF(mx, 0x143));     /* row_bcast:31 */              \
        int me = (__builtin_amdgcn_readlane(__float_as_int(mx), 63) >> 23) & 0xff; \
        float sc = __int_as_float(((me == 0) ? 127 : (254 - me)) << 23);     \
        acc += (me == 0) ? 0 : (me - 127);                                   \
        q0 *= sc; q1 *= sc; q2 *= sc; q3 *= sc;                              \
    }

    while (t + 24 <= tmax) {
        #pragma unroll
        for (int u = 0; u < 24; ++u) {
            float4 p = P[u];
            { int r = t + 24; r = (r > rmax) ? rmax : r;
              P[u] = gb[(size_t)r * 64 + k]; }
            STEP(p)
            if ((u & 3) == 3) RENORM
        }
    }
    while (t + 4 <= tmax) {                  // remainder rows are cache-warm
        { float4 pa = gb[(size_t)t * 64 + k]; STEP(pa) }
        { float4 pb = gb[(size_t)t * 64 + k]; STEP(pb) }
        { float4 pc = gb[(size_t)t * 64 + k]; STEP(pc) }
        { float4 pd = gb[(size_t)t * 64 + k]; STEP(pd) }
        RENORM
    }
    while (t < tmax) {
        float4 pr = gb[(size_t)t * 64 + k]; STEP(pr)
    }
#undef STEP
#undef RENORM

    // final = logaddexp(alpha[2*tl], alpha[2*tl-1]) at t = il-1
    const int e1 = 2 * tl;
    const int e2 = (2 * tl - 1 > 0) ? (2 * tl - 1) : 0;
    const int i1 = e1 & 3, l1 = e1 >> 2;
    const int i2 = e2 & 3, l2 = e2 >> 2;
    float m1 = (i1 == 0) ? q0 : (i1 == 1) ? q1 : (i1 == 2) ? q2 : q3;
    float m2 = (i2 == 0) ? q0 : (i2 == 1) ? q1 : (i2 == 2) ? q2 : q3;
    float ev1 = __shfl(m1, l1, 64);
    float ev2 = __shfl(m2, l2, 64);
    float qs = ev1 + ev2;

    if (k == 0) {
        float loss = 0.0f;
        if (qs > 0.0f && il >= 1 && il <= T) {
            float fin_log2 = (float)acc + log2f(qs);
            loss = -fin_log2 * 0.6931471805599453f;      // ln2
        }
        atomicAdd(out, loss / ((float)tl * (float)B));
    }
}

extern "C" void kernel_launch(void* const* d_in, const int* in_sizes, int n_in,
                              void* d_out, int out_size, void* d_ws, size_t ws_size,
                              hipStream_t stream) {
    const float* pred = (const float*)d_in[0];
    const int*   plen = (const int*)d_in[1];
    const int*   gt   = (const int*)d_in[2];
    const int*   glen = (const int*)d_in[3];
    float* out = (float*)d_out;

    const int B = in_sizes[1];
    const int L = in_sizes[2] / B;
    const int V = 1024;                      // problem-fixed (reference setup)
    const int T = in_sizes[0] / B / V;

    float4* gat = (float4*)d_ws;             // B*T*64 float4 = ~32.8 MiB

    const int nrows = B * T;                 // one wave per row
    const int wavesPerBlk = 4;               // block = 256
    const int nblk = (nrows + wavesPerBlk - 1) / wavesPerBlk;
    lse_gather_kernel<<<nblk, 64 * wavesPerBlk, 0, stream>>>(
        pred, gt, gat, out, T, V, L, nrows);

    ctc_alpha_wave<<<B, 64, 0, stream>>>(gat, gt, plen, glen, out, T, L, B);
}